// Round 4
// baseline (7181.947 us; speedup 1.0000x reference)
//
#include <hip/hip_runtime.h>

#define NB 4096   // batch
#define NH 1024   // hidden
#define NE 512    // embedding dim
#define NV 23     // vocab
#define NT 64     // seq len
#define NL 144    // latent+cond
#define PADV 21
#define SOSV 22

typedef unsigned short u16;
typedef __attribute__((ext_vector_type(16))) float f32x16;
typedef __attribute__((ext_vector_type(8))) __bf16 bf16x8;
typedef __attribute__((ext_vector_type(8))) unsigned short u16x8;

__device__ __forceinline__ u16 f2bf(float x) {
  unsigned u = __float_as_uint(x);
  u += 0x7FFFu + ((u >> 16) & 1u);   // RNE to bf16
  return (u16)(u >> 16);
}
__device__ __forceinline__ float bf2f(u16 h) {
  return __uint_as_float(((unsigned)h) << 16);
}

// h image layout: [mt=m>>8][ks=j>>5][ko=(j>>3)&3][row=m&255][e=j&7]
__device__ __forceinline__ size_t hidx(int m, int j) {
  return ((size_t)(((m >> 8) * 32 + (j >> 5)) * 4 + ((j >> 3) & 3)) * 2048)
         + (size_t)((m & 255) * 8) + (j & 7);
}

// ---------------------------------------------------------------------------
// prep: split W_hh into bf16 hi/lo images (g-major rows for 32x32 MFMA), zero c,
// SOS tokens.  W image row (within jt slice) = g*64 + jl.
__global__ void prep_kernel(const float* __restrict__ Whh, u16* __restrict__ Whi,
                            u16* __restrict__ Wlo, float* __restrict__ c,
                            int* __restrict__ tok) {
  int i = blockIdx.x * 256 + threadIdx.x;   // 4M threads = 4*NH*NH = NB*NH
  float wv = Whh[i];
  u16 hi = f2bf(wv);
  u16 lo = f2bf(wv - bf2f(hi));
  const int nw = i >> 10, k = i & 1023;
  const int g = nw >> 10, jcol = nw & 1023;
  const int jt = jcol >> 6, jl = jcol & 63;
  const int row = g * 64 + jl;
  const size_t oi = ((size_t)((jt * 32 + (k >> 5)) * 4 + ((k >> 3) & 3)) * 2048)
                    + (size_t)(row * 8) + (k & 7);
  Whi[oi] = hi;
  Wlo[oi] = lo;
  c[i] = 0.0f;
  if (i < NB) tok[i] = SOSV;
}

// ---------------------------------------------------------------------------
__global__ void exw_kernel(const float* __restrict__ emb, const float* __restrict__ Wih,
                           const float* __restrict__ bih, const float* __restrict__ bhh,
                           float* __restrict__ ExW) {
  __shared__ float Es[NE];
  const int v = blockIdx.y;
  const int n = blockIdx.x * 256 + threadIdx.x;
  for (int k = threadIdx.x; k < NE; k += 256)
    Es[k] = (v == PADV) ? 0.0f : emb[v * NE + k];
  __syncthreads();
  float s = bih[n] + bhh[n];
  const float* wr = Wih + (long)n * NE;
  for (int k = 0; k < NE; ++k) s = fmaf(Es[k], wr[k], s);
  ExW[v * (4 * NH) + n] = s;
}

// ---------------------------------------------------------------------------
__global__ void h0_kernel(const float* __restrict__ z, const float* __restrict__ cnd,
                          const float* __restrict__ Wlh, const float* __restrict__ blh,
                          u16* __restrict__ hhi, u16* __restrict__ hlo) {
  __shared__ float zc[8][NL];
  const int b0 = blockIdx.y * 8;
  const int j = blockIdx.x * 256 + threadIdx.x;
  for (int idx = threadIdx.x; idx < 8 * NL; idx += 256) {
    int bi = idx / NL, k = idx % NL;
    zc[bi][k] = (k < 128) ? z[(long)(b0 + bi) * 128 + k]
                          : cnd[(long)(b0 + bi) * 16 + (k - 128)];
  }
  __syncthreads();
  float acc[8];
  const float bj = blh[j];
#pragma unroll
  for (int bi = 0; bi < 8; ++bi) acc[bi] = bj;
  const float* wr = Wlh + (long)j * NL;
  for (int k = 0; k < NL; ++k) {
    float wv = wr[k];
#pragma unroll
    for (int bi = 0; bi < 8; ++bi) acc[bi] = fmaf(wv, zc[bi][k], acc[bi]);
  }
#pragma unroll
  for (int bi = 0; bi < 8; ++bi) {
    size_t idx = hidx(b0 + bi, j);
    u16 hi = f2bf(acc[bi]);
    hhi[idx] = hi;
    hlo[idx] = f2bf(acc[bi] - bf2f(hi));
  }
}

// ---------------------------------------------------------------------------
__device__ __forceinline__ void stage8(const u16* __restrict__ src, u16* dst) {
#pragma unroll
  for (int i = 0; i < 8; ++i)
    __builtin_amdgcn_global_load_lds(
        (const __attribute__((address_space(1))) void*)(src + i * 512),
        (__attribute__((address_space(3))) void*)(dst + i * 512), 16, 0, 0);
}

// Fused gates GEMM (split-bf16, 3 MFMA products, 32x32x16) + LSTM cell epilogue.
// 512 thr (8 waves = 4 wm x 2 jh). Tile: 256 m x (64 j x 4 g). BK=32.
// Double-buffered 128 KiB LDS; compiler-scheduled loop, single barrier per iter.
// Inner loop is per-g {2 ds_read_b128 -> 6 MFMA} micro-groups for read/MFMA overlap.
__global__ __launch_bounds__(512, 2)
void gates_cell_kernel(const u16* __restrict__ Whi, const u16* __restrict__ Wlo,
                       const u16* __restrict__ hhi_in, const u16* __restrict__ hlo_in,
                       const float* __restrict__ ExW, const int* __restrict__ tok,
                       float* __restrict__ c, u16* __restrict__ hhi_out,
                       u16* __restrict__ hlo_out) {
  __shared__ u16 lds[65536];   // [4 mats][2 dbuf][8192] : Ahi Alo Bhi Blo

  const int bid = blockIdx.x;                   // 256 blocks = 16 mt x 16 jt
  const int swz = (bid & 7) * 32 + (bid >> 3);  // XCD x owns jt {2x,2x+1}
  const int jt = swz >> 4;
  const int mt = swz & 15;
  const int m0 = mt << 8;
  const int j0 = jt << 6;

  const int tid = threadIdx.x;
  const int w = tid >> 6, l = tid & 63;
  const int wm = w >> 1, jh = w & 1;            // wave tile: 64 m x (32 j x 4 g)
  const int col = l & 31, h5 = l >> 5;

  // staging role: mat = w>>1 (0 Ahi,1 Alo,2 Bhi,3 Blo), hf = w&1 picks 8KB half
  const int mat = w >> 1, hf = w & 1;
  const u16* simg = (mat == 0) ? hhi_in : (mat == 1) ? hlo_in : (mat == 2) ? Whi : Wlo;
  const size_t sbase = ((mat < 2) ? ((size_t)mt * 262144) : ((size_t)jt * 262144))
                       + (size_t)hf * 4096 + (size_t)l * 8;
  const u16* sit = simg + sbase;
  u16* dwave = (u16*)lds + mat * 16384 + hf * 4096;

  f32x16 acc[2][4];   // [mi (32m)][g]
#pragma unroll
  for (int mi = 0; mi < 2; ++mi)
#pragma unroll
    for (int g = 0; g < 4; ++g)
#pragma unroll
      for (int r = 0; r < 16; ++r) acc[mi][g][r] = 0.f;

  stage8(sit, dwave);           // prologue: stage ks=0 into buf 0
  __syncthreads();

  int buf = 0;
  for (int ks = 0; ks < 32; ++ks) {
    if (ks < 31) stage8(sit + (size_t)(ks + 1) * 8192, dwave + (buf ^ 1) * 8192);

    const u16* Ah = lds + buf * 8192;
    const u16* Al = lds + 16384 + buf * 8192;
    const u16* Bh = lds + 32768 + buf * 8192;
    const u16* Bl = lds + 49152 + buf * 8192;

#pragma unroll
    for (int kk = 0; kk < 2; ++kk) {            // two K=16 halves of the K=32 tile
      const int ko = (kk * 2 + h5) * 2048;      // lane's k-octet block
      bf16x8 ah[2], al[2];
#pragma unroll
      for (int mi = 0; mi < 2; ++mi) {
        const int ao = ko + (wm * 64 + mi * 32 + col) * 8;
        ah[mi] = *reinterpret_cast<const bf16x8*>(Ah + ao);
        al[mi] = *reinterpret_cast<const bf16x8*>(Al + ao);
      }
#pragma unroll
      for (int g = 0; g < 4; ++g) {
        const int bo = ko + (g * 64 + jh * 32 + col) * 8;
        const bf16x8 bh = *reinterpret_cast<const bf16x8*>(Bh + bo);
        const bf16x8 bl = *reinterpret_cast<const bf16x8*>(Bl + bo);
        acc[0][g] = __builtin_amdgcn_mfma_f32_32x32x16_bf16(ah[0], bh, acc[0][g], 0, 0, 0);
        acc[1][g] = __builtin_amdgcn_mfma_f32_32x32x16_bf16(ah[1], bh, acc[1][g], 0, 0, 0);
        acc[0][g] = __builtin_amdgcn_mfma_f32_32x32x16_bf16(ah[0], bl, acc[0][g], 0, 0, 0);
        acc[1][g] = __builtin_amdgcn_mfma_f32_32x32x16_bf16(ah[1], bl, acc[1][g], 0, 0, 0);
        acc[0][g] = __builtin_amdgcn_mfma_f32_32x32x16_bf16(al[0], bh, acc[0][g], 0, 0, 0);
        acc[1][g] = __builtin_amdgcn_mfma_f32_32x32x16_bf16(al[1], bh, acc[1][g], 0, 0, 0);
      }
    }
    __syncthreads();   // drains stage (vmcnt0) + lgkm before dbuf reuse
    buf ^= 1;
  }

  // epilogue: + ExW[token], LSTM cell (fp32), write h hi/lo in image layout
  // C/D layout (32x32): col = lane&31, row = (reg&3) + 8*(reg>>2) + 4*(lane>>5)
  const int j = j0 + jh * 32 + col;
#pragma unroll
  for (int mi = 0; mi < 2; ++mi) {
#pragma unroll
    for (int r = 0; r < 16; ++r) {
      const int row = (r & 3) + ((r >> 2) << 3) + (h5 << 2);
      const int m = m0 + wm * 64 + mi * 32 + row;
      const int tk = tok[m];
      const float* exr = ExW + (size_t)tk * 4096;
      const float gi = acc[mi][0][r] + exr[j];
      const float gf = acc[mi][1][r] + exr[NH + j];
      const float gg = acc[mi][2][r] + exr[2 * NH + j];
      const float go = acc[mi][3][r] + exr[3 * NH + j];
      const float i_ = 1.0f / (1.0f + expf(-gi));
      const float f_ = 1.0f / (1.0f + expf(-gf));
      const float g_ = tanhf(gg);
      const float o_ = 1.0f / (1.0f + expf(-go));
      const size_t cidx = (size_t)m * NH + j;
      const float cn = f_ * c[cidx] + i_ * g_;
      c[cidx] = cn;
      const float hn = o_ * tanhf(cn);
      const u16 hi = f2bf(hn);
      const size_t oidx = hidx(m, j);
      hhi_out[oidx] = hi;
      hlo_out[oidx] = f2bf(hn - bf2f(hi));
    }
  }
}

// ---------------------------------------------------------------------------
// logits = h @ W_out^T + b_out ; 8 batch rows per block (amortize W_out reads).
__global__ __launch_bounds__(256)
void logits_kernel(const u16* __restrict__ hhi, const u16* __restrict__ hlo,
                   const float* __restrict__ Wout, const float* __restrict__ bout,
                   float* __restrict__ out, int* __restrict__ tok, int t) {
  __shared__ float hs[8][NH];
  __shared__ float part[8][24][8];
  __shared__ float lg[8][24];
  const int b0 = blockIdx.x * 8;
  const int tid = threadIdx.x;
  for (int ci = tid; ci < 1024; ci += 256) {
    const int bi = ci >> 7, cj = ci & 127;
    const int m = b0 + bi;
    const int ks = cj >> 2, qq = cj & 3;
    const size_t base = ((size_t)(((m >> 8) * 32 + ks) * 4 + qq) * 2048)
                        + (size_t)((m & 255) * 8);
    const u16x8 vh = *reinterpret_cast<const u16x8*>(hhi + base);
    const u16x8 vl = *reinterpret_cast<const u16x8*>(hlo + base);
    const int kb = ks * 32 + qq * 8;
#pragma unroll
    for (int e = 0; e < 8; ++e) hs[bi][kb + e] = bf2f(vh[e]) + bf2f(vl[e]);
  }
  __syncthreads();
  const int v = tid & 31, kc = tid >> 5;
  if (v < NV) {
    float s[8];
#pragma unroll
    for (int bi = 0; bi < 8; ++bi) s[bi] = 0.f;
    const float* wr = Wout + (long)v * NH + kc * 128;
    const int kb = kc * 128;
    for (int k = 0; k < 128; ++k) {
      float wv = wr[k];
#pragma unroll
      for (int bi = 0; bi < 8; ++bi) s[bi] = fmaf(wv, hs[bi][kb + k], s[bi]);
    }
#pragma unroll
    for (int bi = 0; bi < 8; ++bi) part[kc][v][bi] = s[bi];
  }
  __syncthreads();
  if (tid < NV * 8) {
    const int vv = tid >> 3, bi = tid & 7;
    float s = bout[vv];
#pragma unroll
    for (int k = 0; k < 8; ++k) s += part[k][vv][bi];
    lg[bi][vv] = s;
    out[((long)(b0 + bi) * NT + t) * NV + vv] = s;
  }
  __syncthreads();
  if (tid < 8) {
    float best = lg[tid][0];
    int bv = 0;
    for (int vv = 1; vv < NV; ++vv) {
      float x = lg[tid][vv];
      if (x > best) { best = x; bv = vv; }   // strict > : first-max like np.argmax
    }
    tok[b0 + tid] = bv;
  }
}

// ---------------------------------------------------------------------------
extern "C" void kernel_launch(void* const* d_in, const int* in_sizes, int n_in,
                              void* d_out, int out_size, void* d_ws, size_t ws_size,
                              hipStream_t stream) {
  const float* z    = (const float*)d_in[0];
  const float* cnd  = (const float*)d_in[1];
  const float* emb  = (const float*)d_in[2];
  const float* Wlh  = (const float*)d_in[3];
  const float* blh  = (const float*)d_in[4];
  const float* Wih  = (const float*)d_in[5];
  const float* Whh  = (const float*)d_in[6];
  const float* bih  = (const float*)d_in[7];
  const float* bhh  = (const float*)d_in[8];
  const float* Wout = (const float*)d_in[9];
  const float* bout = (const float*)d_in[10];
  float* out = (float*)d_out;

  char* ws = (char*)d_ws;
  size_t off = 0;
  auto alloc = [&](size_t bytes) -> void* {
    off = (off + 255) & ~(size_t)255;
    void* p = ws + off;
    off += bytes;
    return p;
  };
  u16* Whi = (u16*)alloc((size_t)4 * NH * NH * 2);
  u16* Wlo = (u16*)alloc((size_t)4 * NH * NH * 2);
  float* ExW = (float*)alloc((size_t)NV * 4 * NH * 4);
  u16* hhi0 = (u16*)alloc((size_t)NB * NH * 2);
  u16* hhi1 = (u16*)alloc((size_t)NB * NH * 2);
  u16* hlo0 = (u16*)alloc((size_t)NB * NH * 2);
  u16* hlo1 = (u16*)alloc((size_t)NB * NH * 2);
  float* cbuf = (float*)alloc((size_t)NB * NH * 4);
  int* tokb = (int*)alloc((size_t)NB * 4);
  u16* hhi[2] = {hhi0, hhi1};
  u16* hlo[2] = {hlo0, hlo1};

  prep_kernel<<<dim3((4 * NH * NH) / 256), dim3(256), 0, stream>>>(Whh, Whi, Wlo, cbuf, tokb);
  exw_kernel<<<dim3((4 * NH) / 256, NV), dim3(256), 0, stream>>>(emb, Wih, bih, bhh, ExW);
  h0_kernel<<<dim3(NH / 256, NB / 8), dim3(256), 0, stream>>>(z, cnd, Wlh, blh, hhi[0], hlo[0]);

  int p = 0;
  for (int t = 0; t < NT; ++t) {
    gates_cell_kernel<<<dim3(256), dim3(512), 0, stream>>>(
        Whi, Wlo, hhi[p], hlo[p], ExW, tokb, cbuf, hhi[p ^ 1], hlo[p ^ 1]);
    logits_kernel<<<dim3(NB / 8), dim3(256), 0, stream>>>(
        hhi[p ^ 1], hlo[p ^ 1], Wout, bout, out, tokb, t);
    p ^= 1;
  }
}

// Round 5
// 6870.562 us; speedup vs baseline: 1.0453x; 1.0453x over previous
//
#include <hip/hip_runtime.h>

#define NB 4096   // batch
#define NH 1024   // hidden
#define NE 512    // embedding dim
#define NV 23     // vocab
#define NT 64     // seq len
#define NL 144    // latent+cond
#define PADV 21
#define SOSV 22

typedef unsigned short u16;
typedef __attribute__((ext_vector_type(4))) float f32x4;
typedef __attribute__((ext_vector_type(8))) __bf16 bf16x8;
typedef __attribute__((ext_vector_type(8))) unsigned short u16x8;

__device__ __forceinline__ u16 f2bf(float x) {
  unsigned u = __float_as_uint(x);
  u += 0x7FFFu + ((u >> 16) & 1u);   // RNE to bf16
  return (u16)(u >> 16);
}
__device__ __forceinline__ float bf2f(u16 h) {
  return __uint_as_float(((unsigned)h) << 16);
}

// h image layout: [slab=m>>8][ks=j>>5][q=(j>>3)&3][row=m&255][e=j&7]
__device__ __forceinline__ size_t hidx(int m, int j) {
  return ((size_t)(((m >> 8) * 32 + (j >> 5)) * 4 + ((j >> 3) & 3)) * 2048)
         + (size_t)((m & 255) * 8) + (j & 7);
}

// ---------------------------------------------------------------------------
// prep: split W_hh into bf16 hi/lo images (g-major rows), zero c, SOS tokens.
// W image: [jt=j>>6][ks=k>>5][q=(k>>3)&3][row=g*64+(j&63)][e=k&7]
__global__ void prep_kernel(const float* __restrict__ Whh, u16* __restrict__ Whi,
                            u16* __restrict__ Wlo, float* __restrict__ c,
                            int* __restrict__ tok) {
  int i = blockIdx.x * 256 + threadIdx.x;   // 4M threads = 4*NH*NH = NB*NH
  float wv = Whh[i];
  u16 hi = f2bf(wv);
  u16 lo = f2bf(wv - bf2f(hi));
  const int nw = i >> 10, k = i & 1023;
  const int g = nw >> 10, jcol = nw & 1023;
  const int jt = jcol >> 6, jl = jcol & 63;
  const int row = g * 64 + jl;
  const size_t oi = ((size_t)((jt * 32 + (k >> 5)) * 4 + ((k >> 3) & 3)) * 2048)
                    + (size_t)(row * 8) + (k & 7);
  Whi[oi] = hi;
  Wlo[oi] = lo;
  c[i] = 0.0f;
  if (i < NB) tok[i] = SOSV;
}

// ---------------------------------------------------------------------------
__global__ void exw_kernel(const float* __restrict__ emb, const float* __restrict__ Wih,
                           const float* __restrict__ bih, const float* __restrict__ bhh,
                           float* __restrict__ ExW) {
  __shared__ float Es[NE];
  const int v = blockIdx.y;
  const int n = blockIdx.x * 256 + threadIdx.x;
  for (int k = threadIdx.x; k < NE; k += 256)
    Es[k] = (v == PADV) ? 0.0f : emb[v * NE + k];
  __syncthreads();
  float s = bih[n] + bhh[n];
  const float* wr = Wih + (long)n * NE;
  for (int k = 0; k < NE; ++k) s = fmaf(Es[k], wr[k], s);
  ExW[v * (4 * NH) + n] = s;
}

// ---------------------------------------------------------------------------
__global__ void h0_kernel(const float* __restrict__ z, const float* __restrict__ cnd,
                          const float* __restrict__ Wlh, const float* __restrict__ blh,
                          u16* __restrict__ hhi, u16* __restrict__ hlo) {
  __shared__ float zc[8][NL];
  const int b0 = blockIdx.y * 8;
  const int j = blockIdx.x * 256 + threadIdx.x;
  for (int idx = threadIdx.x; idx < 8 * NL; idx += 256) {
    int bi = idx / NL, k = idx % NL;
    zc[bi][k] = (k < 128) ? z[(long)(b0 + bi) * 128 + k]
                          : cnd[(long)(b0 + bi) * 16 + (k - 128)];
  }
  __syncthreads();
  float acc[8];
  const float bj = blh[j];
#pragma unroll
  for (int bi = 0; bi < 8; ++bi) acc[bi] = bj;
  const float* wr = Wlh + (long)j * NL;
  for (int k = 0; k < NL; ++k) {
    float wv = wr[k];
#pragma unroll
    for (int bi = 0; bi < 8; ++bi) acc[bi] = fmaf(wv, zc[bi][k], acc[bi]);
  }
#pragma unroll
  for (int bi = 0; bi < 8; ++bi) {
    size_t idx = hidx(b0 + bi, j);
    u16 hi = f2bf(acc[bi]);
    hhi[idx] = hi;
    hlo[idx] = f2bf(acc[bi] - bf2f(hi));
  }
}

// ---------------------------------------------------------------------------
__device__ __forceinline__ void gll(const u16* src, u16* dst) {
  __builtin_amdgcn_global_load_lds(
      (const __attribute__((address_space(1))) void*)src,
      (__attribute__((address_space(3))) void*)dst, 16, 0, 0);
}

// Fused gates GEMM (split-bf16, 3 MFMA products, 16x16x32) + LSTM cell epilogue.
// 256 thr (4 waves = 2 wm x 2 wn). Tile: 128 m x (64 j x 4 g). BK=32.
// A (h) loaded global->VGPR directly (coalesced via h image), rotated 1 iter ahead.
// B (W) double-buffered in 64 KB LDS -> 2 independent blocks/CU for phase diversity.
__global__ __launch_bounds__(256, 2)
void gates_cell_kernel(const u16* __restrict__ Whi, const u16* __restrict__ Wlo,
                       const u16* __restrict__ hhi_in, const u16* __restrict__ hlo_in,
                       const float* __restrict__ ExW, const int* __restrict__ tok,
                       float* __restrict__ c, u16* __restrict__ hhi_out,
                       u16* __restrict__ hlo_out) {
  __shared__ u16 lds[32768];   // B only: [2 dbuf][2 mats][4 q][256 rows][8e] = 64 KB

  const int bid = blockIdx.x;                 // 512 blocks = 16 jt x 32 bm
  const int swz = (bid & 7) * 64 + (bid >> 3);  // XCD x owns jt {2x,2x+1}
  const int jt = swz >> 5;                    // [0,16)
  const int bm = swz & 31;                    // [0,32)
  const int m0 = bm << 7;
  const int j0 = jt << 6;

  const int tid = threadIdx.x;
  const int w = tid >> 6, l = tid & 63;
  const int wm = w >> 1, wn = w & 1;          // wave tile: 64 m x (32 j x 4 g)
  const int q = l >> 4, rL = l & 15;

  // B staging role: mat = w>>1 (hi/lo), half = w&1 (4KB half of 8KB mat tile)
  const int smat = w >> 1, shalf = w & 1;
  const u16* simg = smat ? Wlo : Whi;
  const size_t sB = (size_t)jt * 262144 + (size_t)shalf * 4096 + (size_t)l * 8;
  u16* sdst0 = (u16*)lds + smat * 8192 + shalf * 4096 + l * 8;

  // A (h) direct-load base: ((slab*32+ks)*4+q)*2048 + (arow0+mi*16)*8
  const int slab = bm >> 1;
  const int arow0 = ((bm & 1) << 7) + wm * 64 + rL;
  const size_t aBase = ((size_t)slab * 128 + q) * 2048 + (size_t)arow0 * 8;

  f32x4 acc[4][8];
#pragma unroll
  for (int mi = 0; mi < 4; ++mi)
#pragma unroll
    for (int ni = 0; ni < 8; ++ni) acc[mi][ni] = (f32x4){0.f, 0.f, 0.f, 0.f};

  bf16x8 A0h[4], A0l[4], A1h[4], A1l[4];

  // prologue: stage B(0) -> buf0, load A(0)
#pragma unroll
  for (int i = 0; i < 8; ++i) gll(simg + sB + i * 512, sdst0 + i * 512);
#pragma unroll
  for (int mi = 0; mi < 4; ++mi) {
    A0h[mi] = *reinterpret_cast<const bf16x8*>(hhi_in + aBase + mi * 128);
    A0l[mi] = *reinterpret_cast<const bf16x8*>(hlo_in + aBase + mi * 128);
  }
  __syncthreads();

  auto body = [&](int ks, int buf, bf16x8* aCh, bf16x8* aCl,
                  bf16x8* aNh, bf16x8* aNl) {
    if (ks < 31) {
      // stage B(ks+1) -> buf^1
      const u16* src = simg + sB + (size_t)(ks + 1) * 8192;
      u16* dst = sdst0 + (buf ^ 1) * 16384;
#pragma unroll
      for (int i = 0; i < 8; ++i) gll(src + i * 512, dst + i * 512);
      // load A(ks+1) into next register set
      const size_t ao = aBase + (size_t)(ks + 1) * 8192;
#pragma unroll
      for (int mi = 0; mi < 4; ++mi) {
        aNh[mi] = *reinterpret_cast<const bf16x8*>(hhi_in + ao + mi * 128);
        aNl[mi] = *reinterpret_cast<const bf16x8*>(hlo_in + ao + mi * 128);
      }
    }
    // B frags from LDS + MFMA (4 independent acc chains per product group)
    const u16* bb = lds + buf * 16384;
#pragma unroll
    for (int ni = 0; ni < 2; ++ni) {
#pragma unroll
      for (int g = 0; g < 4; ++g) {
        const int ro = q * 2048 + (g * 64 + wn * 32 + ni * 16 + rL) * 8;
        const bf16x8 bh = *reinterpret_cast<const bf16x8*>(bb + ro);
        const bf16x8 bl = *reinterpret_cast<const bf16x8*>(bb + 8192 + ro);
        const int ai = g * 2 + ni;
#pragma unroll
        for (int mi = 0; mi < 4; ++mi)
          acc[mi][ai] = __builtin_amdgcn_mfma_f32_16x16x32_bf16(aCh[mi], bh, acc[mi][ai], 0, 0, 0);
#pragma unroll
        for (int mi = 0; mi < 4; ++mi)
          acc[mi][ai] = __builtin_amdgcn_mfma_f32_16x16x32_bf16(aCh[mi], bl, acc[mi][ai], 0, 0, 0);
#pragma unroll
        for (int mi = 0; mi < 4; ++mi)
          acc[mi][ai] = __builtin_amdgcn_mfma_f32_16x16x32_bf16(aCl[mi], bh, acc[mi][ai], 0, 0, 0);
      }
    }
    __syncthreads();   // stages (vmcnt) landed in buf^1; my reads (lgkm) done
  };

  for (int ks2 = 0; ks2 < 32; ks2 += 2) {
    body(ks2, 0, A0h, A0l, A1h, A1l);
    body(ks2 + 1, 1, A1h, A1l, A0h, A0l);
  }

  // epilogue: + ExW[token], LSTM cell (fp32), write h hi/lo in image layout
#pragma unroll
  for (int mi = 0; mi < 4; ++mi) {
#pragma unroll
    for (int r = 0; r < 4; ++r) {
      const int m = m0 + wm * 64 + mi * 16 + q * 4 + r;   // C row = (lane>>4)*4 + reg
      const int tk = tok[m];
      const float* exr = ExW + (size_t)tk * 4096;
#pragma unroll
      for (int ni = 0; ni < 2; ++ni) {
        const int j = j0 + wn * 32 + ni * 16 + rL;         // C col = lane&15
        const float gi = acc[mi][0 * 2 + ni][r] + exr[j];
        const float gf = acc[mi][1 * 2 + ni][r] + exr[NH + j];
        const float gg = acc[mi][2 * 2 + ni][r] + exr[2 * NH + j];
        const float go = acc[mi][3 * 2 + ni][r] + exr[3 * NH + j];
        const float i_ = 1.0f / (1.0f + expf(-gi));
        const float f_ = 1.0f / (1.0f + expf(-gf));
        const float g_ = tanhf(gg);
        const float o_ = 1.0f / (1.0f + expf(-go));
        const size_t cidx = (size_t)m * NH + j;
        const float cn = f_ * c[cidx] + i_ * g_;
        c[cidx] = cn;
        const float hn = o_ * tanhf(cn);
        const u16 hi = f2bf(hn);
        const size_t oidx = hidx(m, j);
        hhi_out[oidx] = hi;
        hlo_out[oidx] = f2bf(hn - bf2f(hi));
      }
    }
  }
}

// ---------------------------------------------------------------------------
// logits = h @ W_out^T + b_out ; 8 batch rows per block (amortize W_out reads).
__global__ __launch_bounds__(256)
void logits_kernel(const u16* __restrict__ hhi, const u16* __restrict__ hlo,
                   const float* __restrict__ Wout, const float* __restrict__ bout,
                   float* __restrict__ out, int* __restrict__ tok, int t) {
  __shared__ float hs[8][NH];
  __shared__ float part[8][24][8];
  __shared__ float lg[8][24];
  const int b0 = blockIdx.x * 8;
  const int tid = threadIdx.x;
  for (int ci = tid; ci < 1024; ci += 256) {
    const int bi = ci >> 7, cj = ci & 127;
    const int m = b0 + bi;
    const int ks = cj >> 2, qq = cj & 3;
    const size_t base = ((size_t)(((m >> 8) * 32 + ks) * 4 + qq) * 2048)
                        + (size_t)((m & 255) * 8);
    const u16x8 vh = *reinterpret_cast<const u16x8*>(hhi + base);
    const u16x8 vl = *reinterpret_cast<const u16x8*>(hlo + base);
    const int kb = ks * 32 + qq * 8;
#pragma unroll
    for (int e = 0; e < 8; ++e) hs[bi][kb + e] = bf2f(vh[e]) + bf2f(vl[e]);
  }
  __syncthreads();
  const int v = tid & 31, kc = tid >> 5;
  if (v < NV) {
    float s[8];
#pragma unroll
    for (int bi = 0; bi < 8; ++bi) s[bi] = 0.f;
    const float* wr = Wout + (long)v * NH + kc * 128;
    const int kb = kc * 128;
    for (int k = 0; k < 128; ++k) {
      float wv = wr[k];
#pragma unroll
      for (int bi = 0; bi < 8; ++bi) s[bi] = fmaf(wv, hs[bi][kb + k], s[bi]);
    }
#pragma unroll
    for (int bi = 0; bi < 8; ++bi) part[kc][v][bi] = s[bi];
  }
  __syncthreads();
  if (tid < NV * 8) {
    const int vv = tid >> 3, bi = tid & 7;
    float s = bout[vv];
#pragma unroll
    for (int k = 0; k < 8; ++k) s += part[k][vv][bi];
    lg[bi][vv] = s;
    out[((long)(b0 + bi) * NT + t) * NV + vv] = s;
  }
  __syncthreads();
  if (tid < 8) {
    float best = lg[tid][0];
    int bv = 0;
    for (int vv = 1; vv < NV; ++vv) {
      float x = lg[tid][vv];
      if (x > best) { best = x; bv = vv; }   // strict > : first-max like np.argmax
    }
    tok[b0 + tid] = bv;
  }
}

// ---------------------------------------------------------------------------
extern "C" void kernel_launch(void* const* d_in, const int* in_sizes, int n_in,
                              void* d_out, int out_size, void* d_ws, size_t ws_size,
                              hipStream_t stream) {
  const float* z    = (const float*)d_in[0];
  const float* cnd  = (const float*)d_in[1];
  const float* emb  = (const float*)d_in[2];
  const float* Wlh  = (const float*)d_in[3];
  const float* blh  = (const float*)d_in[4];
  const float* Wih  = (const float*)d_in[5];
  const float* Whh  = (const float*)d_in[6];
  const float* bih  = (const float*)d_in[7];
  const float* bhh  = (const float*)d_in[8];
  const float* Wout = (const float*)d_in[9];
  const float* bout = (const float*)d_in[10];
  float* out = (float*)d_out;

  char* ws = (char*)d_ws;
  size_t off = 0;
  auto alloc = [&](size_t bytes) -> void* {
    off = (off + 255) & ~(size_t)255;
    void* p = ws + off;
    off += bytes;
    return p;
  };
  u16* Whi = (u16*)alloc((size_t)4 * NH * NH * 2);
  u16* Wlo = (u16*)alloc((size_t)4 * NH * NH * 2);
  float* ExW = (float*)alloc((size_t)NV * 4 * NH * 4);
  u16* hhi0 = (u16*)alloc((size_t)NB * NH * 2);
  u16* hhi1 = (u16*)alloc((size_t)NB * NH * 2);
  u16* hlo0 = (u16*)alloc((size_t)NB * NH * 2);
  u16* hlo1 = (u16*)alloc((size_t)NB * NH * 2);
  float* cbuf = (float*)alloc((size_t)NB * NH * 4);
  int* tokb = (int*)alloc((size_t)NB * 4);
  u16* hhi[2] = {hhi0, hhi1};
  u16* hlo[2] = {hlo0, hlo1};

  prep_kernel<<<dim3((4 * NH * NH) / 256), dim3(256), 0, stream>>>(Whh, Whi, Wlo, cbuf, tokb);
  exw_kernel<<<dim3((4 * NH) / 256, NV), dim3(256), 0, stream>>>(emb, Wih, bih, bhh, ExW);
  h0_kernel<<<dim3(NH / 256, NB / 8), dim3(256), 0, stream>>>(z, cnd, Wlh, blh, hhi[0], hlo[0]);

  int p = 0;
  for (int t = 0; t < NT; ++t) {
    gates_cell_kernel<<<dim3(512), dim3(256), 0, stream>>>(
        Whi, Wlo, hhi[p], hlo[p], ExW, tokb, cbuf, hhi[p ^ 1], hlo[p ^ 1]);
    logits_kernel<<<dim3(NB / 8), dim3(256), 0, stream>>>(
        hhi[p ^ 1], hlo[p ^ 1], Wout, bout, out, tokb, t);
    p ^= 1;
  }
}

// Round 6
// 6390.009 us; speedup vs baseline: 1.1239x; 1.0752x over previous
//
#include <hip/hip_runtime.h>

#define NB 4096   // batch
#define NH 1024   // hidden
#define NE 512    // embedding dim
#define NV 23     // vocab
#define NT 64     // seq len
#define NL 144    // latent+cond
#define PADV 21
#define SOSV 22

typedef unsigned short u16;
typedef __attribute__((ext_vector_type(4))) float f32x4;
typedef __attribute__((ext_vector_type(8))) __bf16 bf16x8;
typedef __attribute__((ext_vector_type(8))) unsigned short u16x8;

__device__ __forceinline__ u16 f2bf(float x) {
  unsigned u = __float_as_uint(x);
  u += 0x7FFFu + ((u >> 16) & 1u);   // RNE to bf16
  return (u16)(u >> 16);
}
__device__ __forceinline__ float bf2f(u16 h) {
  return __uint_as_float(((unsigned)h) << 16);
}

// h image layout: [mt=m>>8][ks=j>>5][q=(j>>3)&3][row=m&255][e=j&7]
__device__ __forceinline__ size_t hidx(int m, int j) {
  return ((size_t)(((m >> 8) * 32 + (j >> 5)) * 4 + ((j >> 3) & 3)) * 2048)
         + (size_t)((m & 255) * 8) + (j & 7);
}

// ---------------------------------------------------------------------------
// prep: split W_hh into bf16 hi/lo *images* (blocked LDS layout), zero c, SOS tok.
// W image row (within jt slice) = (jl>>4)*64 + g*16 + (jl&15)
__global__ void prep_kernel(const float* __restrict__ Whh, u16* __restrict__ Whi,
                            u16* __restrict__ Wlo, float* __restrict__ c,
                            int* __restrict__ tok) {
  int i = blockIdx.x * 256 + threadIdx.x;   // 4M threads = 4*NH*NH = NB*NH
  float wv = Whh[i];
  u16 hi = f2bf(wv);
  u16 lo = f2bf(wv - bf2f(hi));
  const int nw = i >> 10, k = i & 1023;
  const int g = nw >> 10, jcol = nw & 1023;
  const int jt = jcol >> 6, jl = jcol & 63;
  const int row = ((jl >> 4) << 6) + (g << 4) + (jl & 15);
  const size_t oi = ((size_t)((jt * 32 + (k >> 5)) * 4 + ((k >> 3) & 3)) * 2048)
                    + (size_t)(row * 8) + (k & 7);
  Whi[oi] = hi;
  Wlo[oi] = lo;
  c[i] = 0.0f;
  if (i < NB) tok[i] = SOSV;
}

// ---------------------------------------------------------------------------
__global__ void exw_kernel(const float* __restrict__ emb, const float* __restrict__ Wih,
                           const float* __restrict__ bih, const float* __restrict__ bhh,
                           float* __restrict__ ExW) {
  __shared__ float Es[NE];
  const int v = blockIdx.y;
  const int n = blockIdx.x * 256 + threadIdx.x;
  for (int k = threadIdx.x; k < NE; k += 256)
    Es[k] = (v == PADV) ? 0.0f : emb[v * NE + k];
  __syncthreads();
  float s = bih[n] + bhh[n];
  const float* wr = Wih + (long)n * NE;
  for (int k = 0; k < NE; ++k) s = fmaf(Es[k], wr[k], s);
  ExW[v * (4 * NH) + n] = s;
}

// ---------------------------------------------------------------------------
__global__ void h0_kernel(const float* __restrict__ z, const float* __restrict__ cnd,
                          const float* __restrict__ Wlh, const float* __restrict__ blh,
                          u16* __restrict__ hhi, u16* __restrict__ hlo) {
  __shared__ float zc[8][NL];
  const int b0 = blockIdx.y * 8;
  const int j = blockIdx.x * 256 + threadIdx.x;
  for (int idx = threadIdx.x; idx < 8 * NL; idx += 256) {
    int bi = idx / NL, k = idx % NL;
    zc[bi][k] = (k < 128) ? z[(long)(b0 + bi) * 128 + k]
                          : cnd[(long)(b0 + bi) * 16 + (k - 128)];
  }
  __syncthreads();
  float acc[8];
  const float bj = blh[j];
#pragma unroll
  for (int bi = 0; bi < 8; ++bi) acc[bi] = bj;
  const float* wr = Wlh + (long)j * NL;
  for (int k = 0; k < NL; ++k) {
    float wv = wr[k];
#pragma unroll
    for (int bi = 0; bi < 8; ++bi) acc[bi] = fmaf(wv, zc[bi][k], acc[bi]);
  }
#pragma unroll
  for (int bi = 0; bi < 8; ++bi) {
    size_t idx = hidx(b0 + bi, j);
    u16 hi = f2bf(acc[bi]);
    hhi[idx] = hi;
    hlo[idx] = f2bf(acc[bi] - bf2f(hi));
  }
}

// ---------------------------------------------------------------------------
__device__ __forceinline__ void stage1(const u16* __restrict__ src, u16* dst, int i) {
  __builtin_amdgcn_global_load_lds(
      (const __attribute__((address_space(1))) void*)(src + i * 512),
      (__attribute__((address_space(3))) void*)(dst + i * 512), 16, 0, 0);
}

// Fused gates GEMM (split-bf16, 3 MFMA products) + LSTM cell epilogue.
// 512 thr (8 waves). Tile: 256 m x (64 j x 4 g). BK=32. Double-buffered 128 KiB LDS.
// m201-style 4-phase K-iter: {4 ds_read (pair p) -> s_barrier -> gll stages ->
// setprio 24-MFMA cluster}. Counted stage slack; no sched_barrier pins.
__global__ __launch_bounds__(512, 2)
void gates_cell_kernel(const u16* __restrict__ Whi, const u16* __restrict__ Wlo,
                       const u16* __restrict__ hhi_in, const u16* __restrict__ hlo_in,
                       const float* __restrict__ ExW, const int* __restrict__ tok,
                       float* __restrict__ c, u16* __restrict__ hhi_out,
                       u16* __restrict__ hlo_out) {
  __shared__ u16 lds[65536];   // [4 mats][2 dbuf][8192] : Ahi Alo Bhi Blo

  const int bid = blockIdx.x;                   // 256 blocks = 16 mt x 16 jt
  const int swz = (bid & 7) * 32 + (bid >> 3);  // XCD x owns jt {2x,2x+1}
  const int jt = swz >> 4;
  const int mt = swz & 15;
  const int m0 = mt << 8;
  const int j0 = jt << 6;

  const int tid = threadIdx.x;
  const int w = tid >> 6, l = tid & 63;
  const int wm = w >> 1, wn = w & 1;
  const int q = l >> 4, rL = l & 15;

  const int mat = w >> 1, hf = w & 1;
  const u16* simg = (mat == 0) ? hhi_in : (mat == 1) ? hlo_in : (mat == 2) ? Whi : Wlo;
  const size_t sbase = ((mat < 2) ? ((size_t)mt * 262144) : ((size_t)jt * 262144))
                       + (size_t)hf * 4096 + (size_t)l * 8;
  const u16* sit = simg + sbase;
  u16* dwave = (u16*)lds + mat * 16384 + hf * 4096;

  // prefetch greedy tokens for this thread's 16 output rows
  int tkv[16];
#pragma unroll
  for (int mi = 0; mi < 4; ++mi)
#pragma unroll
    for (int r = 0; r < 4; ++r)
      tkv[mi * 4 + r] = tok[m0 + wm * 64 + mi * 16 + q * 4 + r];

  f32x4 acc[4][8];
#pragma unroll
  for (int mi = 0; mi < 4; ++mi)
#pragma unroll
    for (int ni = 0; ni < 8; ++ni) acc[mi][ni] = (f32x4){0.f, 0.f, 0.f, 0.f};

  const int qoff = q * 2048 + rL * 8;

  bf16x8 ah[4], al[4];
  auto mf12 = [&](int ni, const bf16x8 bh, const bf16x8 bl) {
#pragma unroll
    for (int mi = 0; mi < 4; ++mi)
      acc[mi][ni] = __builtin_amdgcn_mfma_f32_16x16x32_bf16(ah[mi], bh, acc[mi][ni], 0, 0, 0);
#pragma unroll
    for (int mi = 0; mi < 4; ++mi)
      acc[mi][ni] = __builtin_amdgcn_mfma_f32_16x16x32_bf16(ah[mi], bl, acc[mi][ni], 0, 0, 0);
#pragma unroll
    for (int mi = 0; mi < 4; ++mi)
      acc[mi][ni] = __builtin_amdgcn_mfma_f32_16x16x32_bf16(al[mi], bh, acc[mi][ni], 0, 0, 0);
  };

  // prologue: stage ks=0 -> buf0, drain, sync
#pragma unroll
  for (int i = 0; i < 8; ++i) stage1(sit, dwave, i);
  asm volatile("s_waitcnt vmcnt(0)" ::: "memory");
  __builtin_amdgcn_s_barrier();

  for (int ks = 0; ks < 32; ++ks) {
    const int buf = ks & 1;
    const u16* ab = lds + buf * 8192 + qoff + wm * 512;
    const u16* bb = lds + 32768 + buf * 8192 + qoff + wn * 1024;
    const u16* snext = sit + (size_t)(ks + 1) * 8192;
    u16* dnext = dwave + (buf ^ 1) * 8192;
    const bool st = (ks < 31);

    // ---- P0: A(8) + B pair0 reads | barrier | stage 0-3 | MFMA ni 0,1 ----
    {
#pragma unroll
      for (int mi = 0; mi < 4; ++mi) {
        ah[mi] = *reinterpret_cast<const bf16x8*>(ab + mi * 128);
        al[mi] = *reinterpret_cast<const bf16x8*>(ab + 16384 + mi * 128);
      }
      const bf16x8 b0h = *reinterpret_cast<const bf16x8*>(bb + 0 * 128);
      const bf16x8 b0l = *reinterpret_cast<const bf16x8*>(bb + 16384 + 0 * 128);
      const bf16x8 b1h = *reinterpret_cast<const bf16x8*>(bb + 1 * 128);
      const bf16x8 b1l = *reinterpret_cast<const bf16x8*>(bb + 16384 + 1 * 128);
      __builtin_amdgcn_s_barrier();
      if (st) { stage1(snext, dnext, 0); stage1(snext, dnext, 1);
                stage1(snext, dnext, 2); stage1(snext, dnext, 3); }
      __builtin_amdgcn_s_setprio(1);
      mf12(0, b0h, b0l);
      mf12(1, b1h, b1l);
      __builtin_amdgcn_s_setprio(0);
    }
    // ---- P1: B pair1 | barrier | stage 4-7 | MFMA ni 2,3 ----
    {
      const bf16x8 b0h = *reinterpret_cast<const bf16x8*>(bb + 2 * 128);
      const bf16x8 b0l = *reinterpret_cast<const bf16x8*>(bb + 16384 + 2 * 128);
      const bf16x8 b1h = *reinterpret_cast<const bf16x8*>(bb + 3 * 128);
      const bf16x8 b1l = *reinterpret_cast<const bf16x8*>(bb + 16384 + 3 * 128);
      __builtin_amdgcn_s_barrier();
      if (st) { stage1(snext, dnext, 4); stage1(snext, dnext, 5);
                stage1(snext, dnext, 6); stage1(snext, dnext, 7); }
      __builtin_amdgcn_s_setprio(1);
      mf12(2, b0h, b0l);
      mf12(3, b1h, b1l);
      __builtin_amdgcn_s_setprio(0);
    }
    // ---- P2: B pair2 | barrier | MFMA ni 4,5 ----
    {
      const bf16x8 b0h = *reinterpret_cast<const bf16x8*>(bb + 4 * 128);
      const bf16x8 b0l = *reinterpret_cast<const bf16x8*>(bb + 16384 + 4 * 128);
      const bf16x8 b1h = *reinterpret_cast<const bf16x8*>(bb + 5 * 128);
      const bf16x8 b1l = *reinterpret_cast<const bf16x8*>(bb + 16384 + 5 * 128);
      __builtin_amdgcn_s_barrier();
      __builtin_amdgcn_s_setprio(1);
      mf12(4, b0h, b0l);
      mf12(5, b1h, b1l);
      __builtin_amdgcn_s_setprio(0);
    }
    // ---- P3: B pair3 | barrier | MFMA ni 6,7 ----
    {
      const bf16x8 b0h = *reinterpret_cast<const bf16x8*>(bb + 6 * 128);
      const bf16x8 b0l = *reinterpret_cast<const bf16x8*>(bb + 16384 + 6 * 128);
      const bf16x8 b1h = *reinterpret_cast<const bf16x8*>(bb + 7 * 128);
      const bf16x8 b1l = *reinterpret_cast<const bf16x8*>(bb + 16384 + 7 * 128);
      __builtin_amdgcn_s_barrier();
      __builtin_amdgcn_s_setprio(1);
      mf12(6, b0h, b0l);
      mf12(7, b1h, b1l);
      __builtin_amdgcn_s_setprio(0);
    }
    // ---- iter end: my stages (issued >=2 phases ago) drained; all waves done ----
    if (st) {
      asm volatile("s_waitcnt vmcnt(0)" ::: "memory");
      __builtin_amdgcn_s_barrier();
    }
  }

  // epilogue: + ExW[token], LSTM cell (fp32), write h hi/lo in image layout
#pragma unroll
  for (int mi = 0; mi < 4; ++mi) {
#pragma unroll
    for (int r = 0; r < 4; ++r) {
      const int m = m0 + wm * 64 + mi * 16 + q * 4 + r;   // C row = (lane>>4)*4 + reg
      const float* exr = ExW + (size_t)tkv[mi * 4 + r] * 4096;
#pragma unroll
      for (int jh = 0; jh < 2; ++jh) {
        const int j = j0 + (wn * 2 + jh) * 16 + rL;        // C col = lane&15
        const float gi = acc[mi][jh * 4 + 0][r] + exr[j];
        const float gf = acc[mi][jh * 4 + 1][r] + exr[NH + j];
        const float gg = acc[mi][jh * 4 + 2][r] + exr[2 * NH + j];
        const float go = acc[mi][jh * 4 + 3][r] + exr[3 * NH + j];
        const float i_ = 1.0f / (1.0f + expf(-gi));
        const float f_ = 1.0f / (1.0f + expf(-gf));
        const float g_ = tanhf(gg);
        const float o_ = 1.0f / (1.0f + expf(-go));
        const size_t cidx = (size_t)m * NH + j;
        const float cn = f_ * c[cidx] + i_ * g_;
        c[cidx] = cn;
        const float hn = o_ * tanhf(cn);
        const u16 hi = f2bf(hn);
        const size_t oidx = hidx(m, j);
        hhi_out[oidx] = hi;
        hlo_out[oidx] = f2bf(hn - bf2f(hi));
      }
    }
  }
}

// ---------------------------------------------------------------------------
// logits = h @ W_out^T + b_out ; 8 batch rows per block (amortize W_out reads).
__global__ __launch_bounds__(256)
void logits_kernel(const u16* __restrict__ hhi, const u16* __restrict__ hlo,
                   const float* __restrict__ Wout, const float* __restrict__ bout,
                   float* __restrict__ out, int* __restrict__ tok, int t) {
  __shared__ float hs[8][NH];
  __shared__ float part[8][24][8];
  __shared__ float lg[8][24];
  const int b0 = blockIdx.x * 8;
  const int tid = threadIdx.x;
  for (int ci = tid; ci < 1024; ci += 256) {
    const int bi = ci >> 7, cj = ci & 127;
    const int m = b0 + bi;
    const int ks = cj >> 2, qq = cj & 3;
    const size_t base = ((size_t)(((m >> 8) * 32 + ks) * 4 + qq) * 2048)
                        + (size_t)((m & 255) * 8);
    const u16x8 vh = *reinterpret_cast<const u16x8*>(hhi + base);
    const u16x8 vl = *reinterpret_cast<const u16x8*>(hlo + base);
    const int kb = ks * 32 + qq * 8;
#pragma unroll
    for (int e = 0; e < 8; ++e) hs[bi][kb + e] = bf2f(vh[e]) + bf2f(vl[e]);
  }
  __syncthreads();
  const int v = tid & 31, kc = tid >> 5;
  if (v < NV) {
    float s[8];
#pragma unroll
    for (int bi = 0; bi < 8; ++bi) s[bi] = 0.f;
    const float* wr = Wout + (long)v * NH + kc * 128;
    const int kb = kc * 128;
    for (int k = 0; k < 128; ++k) {
      float wv = wr[k];
#pragma unroll
      for (int bi = 0; bi < 8; ++bi) s[bi] = fmaf(wv, hs[bi][kb + k], s[bi]);
    }
#pragma unroll
    for (int bi = 0; bi < 8; ++bi) part[kc][v][bi] = s[bi];
  }
  __syncthreads();
  if (tid < NV * 8) {
    const int vv = tid >> 3, bi = tid & 7;
    float s = bout[vv];
#pragma unroll
    for (int k = 0; k < 8; ++k) s += part[k][vv][bi];
    lg[bi][vv] = s;
    out[((long)(b0 + bi) * NT + t) * NV + vv] = s;
  }
  __syncthreads();
  if (tid < 8) {
    float best = lg[tid][0];
    int bv = 0;
    for (int vv = 1; vv < NV; ++vv) {
      float x = lg[tid][vv];
      if (x > best) { best = x; bv = vv; }   // strict > : first-max like np.argmax
    }
    tok[b0 + tid] = bv;
  }
}

// ---------------------------------------------------------------------------
extern "C" void kernel_launch(void* const* d_in, const int* in_sizes, int n_in,
                              void* d_out, int out_size, void* d_ws, size_t ws_size,
                              hipStream_t stream) {
  const float* z    = (const float*)d_in[0];
  const float* cnd  = (const float*)d_in[1];
  const float* emb  = (const float*)d_in[2];
  const float* Wlh  = (const float*)d_in[3];
  const float* blh  = (const float*)d_in[4];
  const float* Wih  = (const float*)d_in[5];
  const float* Whh  = (const float*)d_in[6];
  const float* bih  = (const float*)d_in[7];
  const float* bhh  = (const float*)d_in[8];
  const float* Wout = (const float*)d_in[9];
  const float* bout = (const float*)d_in[10];
  float* out = (float*)d_out;

  char* ws = (char*)d_ws;
  size_t off = 0;
  auto alloc = [&](size_t bytes) -> void* {
    off = (off + 255) & ~(size_t)255;
    void* p = ws + off;
    off += bytes;
    return p;
  };
  u16* Whi = (u16*)alloc((size_t)4 * NH * NH * 2);
  u16* Wlo = (u16*)alloc((size_t)4 * NH * NH * 2);
  float* ExW = (float*)alloc((size_t)NV * 4 * NH * 4);
  u16* hhi0 = (u16*)alloc((size_t)NB * NH * 2);
  u16* hhi1 = (u16*)alloc((size_t)NB * NH * 2);
  u16* hlo0 = (u16*)alloc((size_t)NB * NH * 2);
  u16* hlo1 = (u16*)alloc((size_t)NB * NH * 2);
  float* cbuf = (float*)alloc((size_t)NB * NH * 4);
  int* tokb = (int*)alloc((size_t)NB * 4);
  u16* hhi[2] = {hhi0, hhi1};
  u16* hlo[2] = {hlo0, hlo1};

  prep_kernel<<<dim3((4 * NH * NH) / 256), dim3(256), 0, stream>>>(Whh, Whi, Wlo, cbuf, tokb);
  exw_kernel<<<dim3((4 * NH) / 256, NV), dim3(256), 0, stream>>>(emb, Wih, bih, bhh, ExW);
  h0_kernel<<<dim3(NH / 256, NB / 8), dim3(256), 0, stream>>>(z, cnd, Wlh, blh, hhi[0], hlo[0]);

  int p = 0;
  for (int t = 0; t < NT; ++t) {
    gates_cell_kernel<<<dim3(256), dim3(512), 0, stream>>>(
        Whi, Wlo, hhi[p], hlo[p], ExW, tokb, cbuf, hhi[p ^ 1], hlo[p ^ 1]);
    logits_kernel<<<dim3(NB / 8), dim3(256), 0, stream>>>(
        hhi[p ^ 1], hlo[p ^ 1], Wout, bout, out, tokb, t);
    p ^= 1;
  }
}